// Round 12
// baseline (362.050 us; speedup 1.0000x reference)
//
#include <hip/hip_runtime.h>
#include <hip/hip_bf16.h>

typedef __bf16 bf16;
typedef __bf16 bf16x8 __attribute__((ext_vector_type(8)));
typedef float f32x4 __attribute__((ext_vector_type(4)));
typedef float f32x16 __attribute__((ext_vector_type(16)));
typedef float f32x2u __attribute__((ext_vector_type(2))) __attribute__((aligned(4)));
typedef int  i32x4 __attribute__((ext_vector_type(4)));

#define MFMA32(a, b, c) __builtin_amdgcn_mfma_f32_32x32x16_bf16((a), (b), (c), 0, 0, 0)

// ---- ws layout (bytes) ----
static constexpr size_t FEATS_OFF = 0;                    // featS: 4,194,304 bf16 = 8,388,608
static constexpr size_t OMW_OFF   = 8388608;              // 995,328 bf16 = 1,990,656
static constexpr size_t DCW_OFF   = OMW_OFF + 1990656;    // 36,864 bf16  = 73,728
static constexpr size_t SC_OFF    = DCW_OFF + 73728;      // 2,304 f32    = 9,216
static constexpr size_t PAD_OFF   = SC_OFF + 9216;        // 256*134*134 f32 = 18,386,944

// ---------------- prep kernels ----------------

// feat [b][cf][hh][px] f32 -> featS [b][hh][px][cf swizzled] bf16
// 16B block cfb stored at position (cfb ^ (px&7))
__global__ void prep_featS(const float* __restrict__ feat, bf16* __restrict__ featS) {
    const int hh = blockIdx.x, b = blockIdx.y;
    __shared__ float t[64][129];
    for (int i = threadIdx.x; i < 64 * 32; i += 256) {
        int cf = i >> 5, q = i & 31;
        const float* src = feat + ((size_t)(b * 64 + cf) * 128 + hh) * 128 + q * 4;
        t[cf][q * 4 + 0] = src[0];
        t[cf][q * 4 + 1] = src[1];
        t[cf][q * 4 + 2] = src[2];
        t[cf][q * 4 + 3] = src[3];
    }
    __syncthreads();
    for (int i = threadIdx.x; i < 1024; i += 256) {
        int px = i >> 3, cfb = i & 7;
        int sb = cfb ^ (px & 7);
        bf16x8 v;
#pragma unroll
        for (int e = 0; e < 8; ++e) v[e] = (bf16)t[cfb * 8 + e][px];
        *(bf16x8*)(featS + ((size_t)((b * 128 + hh) * 128 + px) << 6) + sb * 8) = v;
    }
}

// omw32 [blk 9][mt 6 = t*2+ckh][s 36][lane 64][j 8]:
//   A-frag 32x32x16: row = lane&31 -> ck = blk*64+ckh*32+row; k = s*16+(lane>>5)*8+j
// dcw32 [blk 9][ckh 2][ki 2][ot 2][lane 64][j 8]:
//   permuted-K A for GEMM2: o = ot*32+(lane&31);
//   ck = blk*64+ckh*32+ki*16+(j&3)+8*(j>>2)+4*(lane>>5)
// sconst f32x4[...]: idx = ((blk*2+ckh)*2+hi)*16 + g*4 + f; elems e: ck = blk*64+ckh*32+8g+4hi+e
__global__ void prep_weights(const float* __restrict__ om_w, const float* __restrict__ om_b,
                             const float* __restrict__ dc_w,
                             bf16* __restrict__ omw32, bf16* __restrict__ dcw32,
                             float* __restrict__ scf) {
    int i = blockIdx.x * 256 + threadIdx.x;
    if (i < 995328) {
        int j = i & 7, lane = (i >> 3) & 63;
        int rest = i >> 9;          // (blk*6 + mt)*36 + s
        int s = rest % 36, rest2 = rest / 36;
        int mt = rest2 % 6, blk = rest2 / 6;
        int t = mt >> 1, ckh = mt & 1;
        int ck = blk * 64 + ckh * 32 + (lane & 31);
        int kcol = s * 16 + (lane >> 5) * 8 + j;
        int tap = kcol >> 6, cf = kcol & 63;
        int ch = (t < 2) ? (ck * 2 + t) : (1152 + ck);
        omw32[i] = (bf16)om_w[ch * 576 + cf * 9 + tap];
    }
    if (i < 36864) {
        int j = i & 7, lane = (i >> 3) & 63;
        int rest = i >> 9;          // ((blk*2+ckh)*2+ki)*2 + ot
        int ot = rest & 1, ki = (rest >> 1) & 1, ckh = (rest >> 2) & 1, blk = rest >> 3;
        int o = ot * 32 + (lane & 31);
        int ck = blk * 64 + ckh * 32 + ki * 16 + (j & 3) + 8 * (j >> 2) + 4 * (lane >> 5);
        dcw32[i] = (bf16)dc_w[o * 576 + ck];
    }
    if (i < 2304) {
        int e = i & 3, vi = i >> 2;
        int f = vi & 3, g = (vi >> 2) & 3, hi = (vi >> 4) & 1, ckh = (vi >> 5) & 1, blk = vi >> 6;
        int ck = blk * 64 + ckh * 32 + 8 * g + 4 * hi + e;
        int c = ck / 9, kd = ck - 9 * c, kq = kd / 3, kx = kd - 3 * kq;
        float v;
        if (f == 0)      v = om_b[2 * ck] + (float)(kq + 2);
        else if (f == 1) v = om_b[2 * ck + 1] + (float)(kx + 2);
        else if (f == 2) v = om_b[1152 + ck];
        else             v = __uint_as_float((unsigned)(c * 17956));
        scf[i] = v;
    }
}

// inputs [256][128][128] -> zero-padded pad [256][134][134] (3-px border)
__global__ void prep_pad(const float* __restrict__ inputs, float* __restrict__ pad) {
    int yy = blockIdx.x, bc = blockIdx.y, xx = threadIdx.x;
    if (xx >= 134) return;
    float v = 0.f;
    if (yy >= 3 && yy <= 130 && xx >= 3 && xx <= 130)
        v = inputs[(size_t)bc * 16384 + (yy - 3) * 128 + (xx - 3)];
    pad[((size_t)bc * 134 + yy) * 134 + xx] = v;
}

// ---------------- fused main kernel ----------------
// grid 1024 = (b,h,pxhalf); 4 waves = (Ntile = px 32-quarter, ckh = ck 32-half).
// All MFMA in 32x32x16. ZERO main-loop barriers:
//   per blk: GEMM1 (3 M-tiles x N=32, K=576; acc1 = 3 f32x16) -> sample 16/lane
//   -> pack B0/B1 -> GEMM2 from registers (permuted-K, acc2 = 2 f32x16 partial
//   over this wave's ck-half). Epilogue: ckh-pair reduce via LDS (2 barriers).

__global__ void __launch_bounds__(256, 3)
deform_fused(const float* __restrict__ pad,
             const bf16* __restrict__ featS,
             const bf16* __restrict__ omw32,
             const bf16* __restrict__ dcw32,
             const f32x4* __restrict__ sconst,
             const float* __restrict__ dcb,
             float* __restrict__ out)
{
    const int bid = blockIdx.x;
    const int P0 = (bid & 1) << 6;
    const int h = (bid >> 1) & 127;
    const int b = bid >> 8;
    const int tid = threadIdx.x;
    const int lane = tid & 63;
    const int wid_s = __builtin_amdgcn_readfirstlane(tid >> 6);
    const int ckh = wid_s & 1, nt = wid_s >> 1;
    const int l31 = lane & 31, hi = lane >> 5;

    __shared__ __align__(16) unsigned char smem[25344];   // featB; epilogue red overlays
    char* featB = (char*)smem;

    // zero featB (halo cols / OOB rows stay 0)
    for (int i = tid; i < 6336; i += 256) ((unsigned*)featB)[i] = 0u;
    __syncthreads();
    // bulk-stage 3 rows x 65 px-cols x 128B from featS (swizzle rides along)
    {
        const int s0 = (P0 == 0) ? 0 : 63;
        const int q0 = (P0 == 0) ? 1 : 0;
        for (int i = tid; i < 1560; i += 256) {
            int ky = i / 520, rem = i - ky * 520, row = rem >> 3, c = rem & 7;
            int hh = h - 1 + ky;
            if ((unsigned)hh < 128u) {
                const char* src = (const char*)featS
                    + (((size_t)(b * 128 + hh) * 128 + s0 + row) << 7) + c * 16;
                *(i32x4*)(featB + ((ky * 66 + q0 + row) << 7) + c * 16) = *(const i32x4*)src;
            }
        }
    }
    __syncthreads();

    // per-lane blk-invariant LDS bases: addr(s) = base9[s>>2] ^ ((s&3)<<5)
    int base9[9];
#pragma unroll
    for (int tap = 0; tap < 9; ++tap) {
        const int kyp = tap / 3, kxp = tap - 3 * kyp;
        const int q = nt * 32 + l31 + kxp;
        base9[tap] = (kyp * 66 + q) * 128 + ((hi ^ ((q + 7) & 7)) << 4);
    }

    f32x16 acc2a = {}, acc2b = {};

    const bf16* omw_l = omw32 + lane * 8;
    const bf16* dcw_l = dcw32 + lane * 8;
    const float* padb0 = pad + (size_t)b * 64 * 17956;
    const float hf = (float)h;
    const float fx = (float)(P0 + nt * 32 + l31);

#pragma unroll 1
    for (int blk = 0; blk < 9; ++blk) {
        // ---- GEMM1: 3 M-tiles (t x this ck-half), N=32, K=576 ----
        f32x16 c0 = {}, c1 = {}, c2 = {};
        const size_t ab = ((size_t)(blk * 216 + ckh * 36)) * 512;   // t-stride = 72*512

#pragma unroll
        for (int s = 0; s < 36; ++s) {
            bf16x8 a0 = *(const bf16x8*)(omw_l + ab + (size_t)s * 512);
            bf16x8 a1 = *(const bf16x8*)(omw_l + ab + (size_t)(s + 72) * 512);
            bf16x8 a2 = *(const bf16x8*)(omw_l + ab + (size_t)(s + 144) * 512);
            bf16x8 bfr = *(const bf16x8*)(featB + (base9[s >> 2] ^ ((s & 3) << 5)));
            __builtin_amdgcn_s_setprio(1);
            c0 = MFMA32(a0, bfr, c0);
            c1 = MFMA32(a1, bfr, c1);
            c2 = MFMA32(a2, bfr, c2);
            __builtin_amdgcn_s_setprio(0);
        }

        // ---- sample: 16 per lane (lane's px fixed; rows crow(r)) ----
        bf16x8 B0 = {}, B1 = {};
        const f32x4* scg = sconst + ((size_t)((blk * 2 + ckh) * 2 + hi)) * 16;
#pragma unroll
        for (int g = 0; g < 4; ++g) {
            f32x4 yb = scg[g * 4 + 0];
            f32x4 xb = scg[g * 4 + 1];
            f32x4 mb = scg[g * 4 + 2];
            f32x4 co = scg[g * 4 + 3];
#pragma unroll
            for (int e = 0; e < 4; ++e) {
                const int r = g * 4 + e;
                float py = c0[r] + yb[e] + hf;
                float px = c1[r] + xb[e] + fx;
                float lg = c2[r] + mb[e];
                float pyc = __builtin_amdgcn_fmed3f(py, 0.5f, 132.5f);
                float pxc = __builtin_amdgcn_fmed3f(px, 0.5f, 132.5f);
                int y0 = (int)pyc, x0 = (int)pxc;       // trunc == floor (>0)
                float wy = __builtin_amdgcn_fractf(pyc);
                float wx = __builtin_amdgcn_fractf(pxc);
                unsigned off = __float_as_uint(co[e]) + (unsigned)(y0 * 134 + x0);
                f32x2u t0 = *(const f32x2u*)(padb0 + off);
                f32x2u t1 = *(const f32x2u*)(padb0 + off + 134);
                float top = t0.x + wx * (t0.y - t0.x);
                float bot = t1.x + wx * (t1.y - t1.x);
                float bil = top + wy * (bot - top);
                float mk = __builtin_amdgcn_rcpf(1.f + __expf(-lg));
                float sv = bil * mk;
                if (r < 8) B0[r] = (bf16)sv;
                else       B1[r - 8] = (bf16)sv;
            }
        }

        // ---- GEMM2 from registers (K=32 = this wave's ck-half, permuted) ----
        const bf16* dk = dcw_l + ((size_t)((blk * 4 + ckh * 2)) << 10);  // *2*512
        bf16x8 aK00 = *(const bf16x8*)(dk);             // ki0, ot0
        bf16x8 aK01 = *(const bf16x8*)(dk + 512);       // ki0, ot1
        bf16x8 aK10 = *(const bf16x8*)(dk + 1024);      // ki1, ot0
        bf16x8 aK11 = *(const bf16x8*)(dk + 1536);      // ki1, ot1
        __builtin_amdgcn_s_setprio(1);
        acc2a = MFMA32(aK00, B0, acc2a);
        acc2b = MFMA32(aK01, B0, acc2b);
        acc2a = MFMA32(aK10, B1, acc2a);
        acc2b = MFMA32(aK11, B1, acc2b);
        __builtin_amdgcn_s_setprio(0);
    }

    // ---- epilogue: ckh-pair reduce via LDS overlay, bias + relu, store ----
    __syncthreads();
    float* red = (float*)smem;   // [2 nt][64 o][32 px]
    if (ckh) {
#pragma unroll
        for (int r = 0; r < 16; ++r) {
            int o0 = (r & 3) + 8 * (r >> 2) + 4 * hi;
            red[(nt * 64 + o0) * 32 + l31] = acc2a[r];
            red[(nt * 64 + 32 + o0) * 32 + l31] = acc2b[r];
        }
    }
    __syncthreads();
    if (!ckh) {
#pragma unroll
        for (int r = 0; r < 16; ++r) {
            int o0 = (r & 3) + 8 * (r >> 2) + 4 * hi;
            {
                int o = o0;
                float v = red[(nt * 64 + o) * 32 + l31] + acc2a[r] + dcb[o];
                out[((size_t)(b * 64 + o) * 128 + h) * 128 + P0 + nt * 32 + l31]
                    = fmaxf(v, 0.f);
            }
            {
                int o = 32 + o0;
                float v = red[(nt * 64 + o) * 32 + l31] + acc2b[r] + dcb[o];
                out[((size_t)(b * 64 + o) * 128 + h) * 128 + P0 + nt * 32 + l31]
                    = fmaxf(v, 0.f);
            }
        }
    }
}

// ---------------- launcher ----------------
extern "C" void kernel_launch(void* const* d_in, const int* in_sizes, int n_in,
                              void* d_out, int out_size, void* d_ws, size_t ws_size,
                              hipStream_t stream) {
    const float* inputs = (const float*)d_in[0];
    const float* feat   = (const float*)d_in[1];
    const float* om_w   = (const float*)d_in[2];
    const float* om_b   = (const float*)d_in[3];
    const float* dc_w   = (const float*)d_in[4];
    const float* dc_b   = (const float*)d_in[5];
    float* out = (float*)d_out;

    char* ws = (char*)d_ws;
    bf16*  featS = (bf16*)(ws + FEATS_OFF);
    bf16*  omw32 = (bf16*)(ws + OMW_OFF);
    bf16*  dcw32 = (bf16*)(ws + DCW_OFF);
    float* scf   = (float*)(ws + SC_OFF);
    float* pad   = (float*)(ws + PAD_OFF);

    prep_featS<<<dim3(128, 4), 256, 0, stream>>>(feat, featS);
    prep_weights<<<(995328 + 255) / 256, 256, 0, stream>>>(om_w, om_b, dc_w, omw32, dcw32, scf);
    prep_pad<<<dim3(134, 256), 256, 0, stream>>>(inputs, pad);

    deform_fused<<<1024, 256, 0, stream>>>(pad, featS, omw32, dcw32,
                                           (const f32x4*)scf, dc_b, out);
}